// Round 18
// baseline (52.553 us; speedup 1.0000x reference)
//
#include <hip/hip_runtime.h>
#include <hip/hip_bf16.h>

namespace {

constexpr int B_ = 4, L = 2048, H = 8, E = 64;
constexpr int RS = H * E;            // 512 floats: row stride in [B,L,H,E]
constexpr float CS = 0.125f * 1.44269504f;  // SCALE * log2(e): exp2-direct
constexpr float THR2 = 11.5f;        // defer-max threshold in log2 units

// split-K partials (floats): acc[2][32][1024rows][64] ++ m ++ l  (R11 layout)
constexpr size_t ACCF = (size_t)2 * 32 * 8 * 128 * 64;
constexpr size_t MOFF = ACCF;
constexpr size_t PART_ROWS = (size_t)32 * 8 * 128;
constexpr size_t LOFF = MOFF + 2 * PART_ROWS;
constexpr size_t PART_FLOATS = LOFF + 2 * PART_ROWS;   // ~17.3 MB

typedef __attribute__((ext_vector_type(8))) short bf16x8;
typedef __attribute__((ext_vector_type(4))) float f32x4;

__device__ inline unsigned cvt2(float a, float b) {
  __hip_bfloat162 hh = __float22bfloat162_rn(make_float2(a, b));  // v_cvt_pk_bf16_f32
  union { __hip_bfloat162 h; unsigned u; } c; c.h = hh; return c.u;
}

// R17 base (512 blocks x 8 waves, pair (g,15-g), two uniform 17-step roles,
// QBLK=16, KVBLK=64, ones-column lsum, setprio, incremental cursors) with
// ONE structural change: 2-step unroll over 4 LDS buffers -> ONE barrier
// per TWO steps (halves barrier drains). Writes always target the buffer
// pair not being read; the pair-barrier orders read-before-overwrite.
__global__ __launch_bounds__(512)
void fa_split(const float* __restrict__ Q, const float* __restrict__ K,
              const float* __restrict__ V, float* __restrict__ O,
              float* __restrict__ ws, int splitMode)
{
  const int tid  = (int)threadIdx.x;
  const int lane = tid & 63;
  const int wv   = tid >> 6;
  const int bi   = (int)blockIdx.x;
  const int bh   = bi & 31;                 // low bits -> XCD L2 locality
  const int pp   = (bi >> 5) & 7;
  const int role = splitMode ? (bi >> 8) : 2;
  const int b = bh >> 3, h = bh & 7;
  const int ln = lane & 15, lg = lane >> 4, d0 = lg * 4;

  // schedule (64-key steps)
  int total, ph1sb0, qgA, k0A, qgB; bool finA, finB; int part;
  const int g = pp, v = 15 - pp;
  if (role == 0)      { total = 17; ph1sb0 = 2*g+2; qgA = g; k0A = 0;        finA = true;  qgB = v; finB = false; part = 0; }
  else if (role == 1) { total = 17; ph1sb0 = 1000;  qgA = v; k0A = 15 - 2*g; finA = false; qgB = 0; finB = false; part = 1; }
  else                { total = 34; ph1sb0 = 2*g+2; qgA = g; k0A = 0;        finA = true;  qgB = v; finB = true;  part = 0; }

  const size_t base = (size_t)b * L * RS + (size_t)h * E;
  const float* Qb = Q + base;
  const float* Kb = K + base;
  const float* Vb = V + base;
  float*       Ob = O + base;

  __shared__ __align__(16) unsigned char KT[4][64 * 128];  // 4 buffers
  __shared__ __align__(16) unsigned char VT[4][64 * 128];

  // ---- staging: incremental pointers, one uint4 LDS write each ----
  const int vdd = tid & 63, vc = tid >> 6;          // V: dim vdd, chunk vc
  const int vkb = 4 * vc + ((vc >> 2) << 4);        // keys vkb..+3, vkb+16..+19
  const int kky = tid >> 3, kc = tid & 7;           // K: key kky, dims 8kc..+7
  float vr[8]; float4 kr0, kr1;
  const float* vp_it;                                // incremental cursors
  const float* kp_it;

  auto stage_seek = [&](int ks) {                    // rebuild cursors (rare)
    const int kv0 = ks * 64;
    vp_it = Vb + (size_t)(kv0 + vkb) * RS + vdd;
    kp_it = Kb + (size_t)(kv0 + kky) * RS + 8 * kc;
  };
  auto stage_load = [&]() {                          // load at cursor, advance
#pragma unroll
    for (int j = 0; j < 4; ++j) vr[j] = vp_it[(size_t)j * RS];
#pragma unroll
    for (int j = 0; j < 4; ++j) vr[4 + j] = vp_it[(size_t)(16 + j) * RS];
    kr0 = *(const float4*)kp_it; kr1 = *(const float4*)(kp_it + 4);
    vp_it += (size_t)64 * RS;
    kp_it += (size_t)64 * RS;
  };
  auto stage_write = [&](int bufI) {
    union { uint4 q; unsigned u[4]; } w;
    w.u[0] = cvt2(vr[0], vr[1]); w.u[1] = cvt2(vr[2], vr[3]);
    w.u[2] = cvt2(vr[4], vr[5]); w.u[3] = cvt2(vr[6], vr[7]);
    *(uint4*)(VT[bufI] + vdd * 128 + 16 * (vc ^ (vdd & 7))) = w.q;
    union { uint4 q; unsigned u[4]; } y;
    y.u[0] = cvt2(kr0.x, kr0.y); y.u[1] = cvt2(kr0.z, kr0.w);
    y.u[2] = cvt2(kr1.x, kr1.y); y.u[3] = cvt2(kr1.z, kr1.w);
    *(uint4*)(KT[bufI] + kky * 128 + 16 * (kc ^ (kky & 7))) = y.q;
  };

  // ---- per-phase state ----
  int qg = qgA; bool curFin = finA;
  int qrow0 = qg * 128 + wv * 16;
  int nsW   = (qrow0 + 79) >> 6;

  bf16x8 qf0, qf1;
  auto load_q = [&]() {                      // Q pre-scaled by CS (exp2 domain)
    const float* qp = Qb + (size_t)(qrow0 + ln) * RS + 8 * lg;
    float4 a = *(const float4*)qp,        c = *(const float4*)(qp + 4);
    float4 d = *(const float4*)(qp + 32), e = *(const float4*)(qp + 36);
    union { bf16x8 v8; unsigned u[4]; } r0, r1;
    r0.u[0] = cvt2(a.x * CS, a.y * CS); r0.u[1] = cvt2(a.z * CS, a.w * CS);
    r0.u[2] = cvt2(c.x * CS, c.y * CS); r0.u[3] = cvt2(c.z * CS, c.w * CS);
    r1.u[0] = cvt2(d.x * CS, d.y * CS); r1.u[1] = cvt2(d.z * CS, d.w * CS);
    r1.u[2] = cvt2(e.x * CS, e.y * CS); r1.u[3] = cvt2(e.z * CS, e.w * CS);
    qf0 = r0.v8; qf1 = r1.v8;
  };
  load_q();

  // ones fragment for the lsum column (bf16 1.0 = 0x3F80)
  union { bf16x8 v8; unsigned u[4]; } ones;
#pragma unroll
  for (int j = 0; j < 4; ++j) ones.u[j] = 0x3F803F80u;

  f32x4 acc[4], acc4;
#pragma unroll
  for (int nt = 0; nt < 4; ++nt) acc[nt] = (f32x4){0.f, 0.f, 0.f, 0.f};
  acc4 = (f32x4){0.f, 0.f, 0.f, 0.f};       // acc4[r] = lsum of q-row d0+r
  float m = -1e30f;

  auto epilogue = [&]() {
    if (curFin) {
#pragma unroll
      for (int r = 0; r < 4; ++r) {
        const float il = 1.0f / acc4[r];
#pragma unroll
        for (int nt = 0; nt < 4; ++nt)
          Ob[(size_t)(qrow0 + d0 + r) * RS + (ln + 16 * nt)] = acc[nt][r] * il;
      }
    } else {
      const int vg = qg - 8;
      const size_t rb = ((size_t)part * 32 + bh) * 1024 + (size_t)vg * 128;
#pragma unroll
      for (int nt = 0; nt < 4; ++nt)
#pragma unroll
        for (int r = 0; r < 4; ++r)
          ws[(rb + wv * 16 + d0 + r) * 64 + ln + 16 * nt] = acc[nt][r];
      if (lane < 16) ws[MOFF + rb + wv * 16 + lane] = m;
      if (ln == 0) {
#pragma unroll
        for (int r = 0; r < 4; ++r)
          ws[LOFF + rb + wv * 16 + d0 + r] = acc4[r];
      }
    }
  };

  auto compute = [&](int kstep, int bufI) {
    if (kstep < nsW) {
      __builtin_amdgcn_s_setprio(1);         // T5: favor compute waves
      const unsigned char* Kt = KT[bufI];
      const int swzr = 16 * (ln & 7);

      f32x4 st[4];
#pragma unroll
      for (int kt = 0; kt < 4; ++kt) {
        const unsigned char* kr = Kt + (16 * kt + ln) * 128;
        const bf16x8 kfa = *(const bf16x8*)(kr + ((16 * lg) ^ swzr));
        const bf16x8 kfb = *(const bf16x8*)(kr + ((16 * lg + 64) ^ swzr));
        f32x4 s = (f32x4){0.f, 0.f, 0.f, 0.f};
        s = __builtin_amdgcn_mfma_f32_16x16x32_bf16(kfa, qf0, s, 0, 0, 0);
        s = __builtin_amdgcn_mfma_f32_16x16x32_bf16(kfb, qf1, s, 0, 0, 0);
        st[kt] = s;
      }

      float x[16];
#pragma unroll
      for (int kt = 0; kt < 4; ++kt)
#pragma unroll
        for (int r = 0; r < 4; ++r) x[4 * kt + r] = st[kt][r];

      if (kstep == nsW - 1) {                // diagonal tile
        const int kv0 = kstep * 64;
        const int qr = qrow0 + ln;
#pragma unroll
        for (int kt = 0; kt < 4; ++kt)
#pragma unroll
          for (int r = 0; r < 4; ++r) {
            const int key = kv0 + 16 * kt + d0 + r;
            if (key > qr) x[4 * kt + r] = -1e30f;
          }
      }

      // per-lane max (tree); rescale only on rare threshold breach
      float t8[8];
#pragma unroll
      for (int e = 0; e < 8; ++e) t8[e] = fmaxf(x[e], x[8 + e]);
      float t4a = fmaxf(t8[0], t8[4]), t4b = fmaxf(t8[1], t8[5]);
      float t4c = fmaxf(t8[2], t8[6]), t4d = fmaxf(t8[3], t8[7]);
      float mx = fmaxf(fmaxf(t4a, t4b), fmaxf(t4c, t4d));

      if (!__all(mx <= m + THR2)) {
        float gm = fmaxf(mx, __shfl_xor(mx, 16, 64));
        gm = fmaxf(gm, __shfl_xor(gm, 32, 64));
        const float newm = fmaxf(m, gm);
        const float sc = __builtin_exp2f(m - newm);
        float scr[4];
#pragma unroll
        for (int r = 0; r < 4; ++r) scr[r] = __shfl(sc, d0 + r, 64);
#pragma unroll
        for (int nt = 0; nt < 4; ++nt) {
          acc[nt][0] *= scr[0]; acc[nt][1] *= scr[1];
          acc[nt][2] *= scr[2]; acc[nt][3] *= scr[3];
        }
        acc4[0] *= scr[0]; acc4[1] *= scr[1];
        acc4[2] *= scr[2]; acc4[3] *= scr[3];
        m = newm;
      }

      float p[16];
#pragma unroll
      for (int e = 0; e < 16; ++e) p[e] = __builtin_exp2f(x[e] - m);

      // PV (+ ones column for lsum): 2 key-groups x (4 dim-tiles + 1)
      const unsigned char* Vt = VT[bufI];
#pragma unroll
      for (int kg = 0; kg < 2; ++kg) {
        union { bf16x8 v8; unsigned u[4]; } pf;
#pragma unroll
        for (int j = 0; j < 4; ++j)
          pf.u[j] = cvt2(p[8 * kg + 2 * j], p[8 * kg + 2 * j + 1]);
#pragma unroll
        for (int nt = 0; nt < 4; ++nt) {
          const int row = ln + 16 * nt;
          const bf16x8 vf = *(const bf16x8*)(
              Vt + row * 128 + 16 * ((lg + 4 * kg) ^ (ln & 7)));
          acc[nt] = __builtin_amdgcn_mfma_f32_16x16x32_bf16(pf.v8, vf, acc[nt], 0, 0, 0);
        }
        acc4 = __builtin_amdgcn_mfma_f32_16x16x32_bf16(pf.v8, ones.v8, acc4, 0, 0, 0);
      }
      __builtin_amdgcn_s_setprio(0);
    }
  };

  auto phase_switch = [&](int sb) {          // block-uniform
    if (sb == ph1sb0 - 1) {
      epilogue();
#pragma unroll
      for (int nt = 0; nt < 4; ++nt) acc[nt] = (f32x4){0.f, 0.f, 0.f, 0.f};
      acc4 = (f32x4){0.f, 0.f, 0.f, 0.f};
      m = -1e30f;
      qg = qgB; curFin = finB;
      qrow0 = qg * 128 + wv * 16;
      nsW = (qrow0 + 79) >> 6;
      load_q();
    }
  };

  auto kstep_of = [&](int sb) { return (sb < ph1sb0) ? (k0A + sb) : (sb - ph1sb0); };

  // ---- prologue: stage steps 0 and 1 (total >= 17, ph1sb0 >= 2) ----
  stage_seek(k0A);
  stage_load(); stage_write(0);
  stage_load(); stage_write(1);
  __syncthreads();

  int bp = 0, sb = 0;
  while (sb + 1 < total) {
    const int r0 = 2 * bp, r1 = r0 + 1;
    const int w0 = 2 * (bp ^ 1), w1 = w0 + 1;

    if (sb + 2 < total) {
      if (sb + 2 == ph1sb0) stage_seek(0);
      stage_load();                          // T14: issue early
    }
    compute(kstep_of(sb), r0);
    phase_switch(sb);
    if (sb + 2 < total) stage_write(w0);

    if (sb + 3 < total) {
      if (sb + 3 == ph1sb0) stage_seek(0);
      stage_load();
    }
    compute(kstep_of(sb + 1), r1);
    phase_switch(sb + 1);
    if (sb + 3 < total) stage_write(w1);

    __syncthreads();                         // ONE barrier per 2 steps
    bp ^= 1;
    sb += 2;
  }
  if (sb < total) {                          // odd tail (split roles: step 16)
    compute(kstep_of(sb), 2 * bp);
    phase_switch(sb);
  }

  epilogue();
}

// Combine the two split-K partials for rows 1024..2047 (VERBATIM from R11).
__global__ __launch_bounds__(256)
void fa_merge(const float* __restrict__ ws, float* __restrict__ O)
{
  const int idx = (int)blockIdx.x * 256 + (int)threadIdx.x;   // 0..524287
  const int d4  = idx & 15;
  const int row = (idx >> 4) & 127;
  const int vg  = (idx >> 11) & 7;
  const int bh  = idx >> 14;
  const size_t rbase = ((size_t)bh * 8 + vg) * 128 + row;

  const float m0 = ws[MOFF + rbase],             l0 = ws[LOFF + rbase];
  const float m1 = ws[MOFF + PART_ROWS + rbase], l1 = ws[LOFF + PART_ROWS + rbase];
  const float M  = fmaxf(m0, m1);
  const float e0 = __builtin_exp2f(m0 - M), e1 = __builtin_exp2f(m1 - M);
  const float inv = 1.0f / (l0 * e0 + l1 * e1);

  const float4 a0 = *(const float4*)(ws + rbase * 64 + 4 * d4);
  const float4 a1 = *(const float4*)(ws + PART_ROWS * 64 + rbase * 64 + 4 * d4);

  const int b = bh >> 3, h = bh & 7;
  const int orow = (8 + vg) * 128 + row;
  float4 o;
  o.x = (a0.x * e0 + a1.x * e1) * inv;
  o.y = (a0.y * e0 + a1.y * e1) * inv;
  o.z = (a0.z * e0 + a1.z * e1) * inv;
  o.w = (a0.w * e0 + a1.w * e1) * inv;
  *(float4*)(O + ((size_t)(b * L + orow) * H + h) * E + 4 * d4) = o;
}

} // namespace

extern "C" void kernel_launch(void* const* d_in, const int* in_sizes, int n_in,
                              void* d_out, int out_size, void* d_ws, size_t ws_size,
                              hipStream_t stream) {
  const float* Q = (const float*)d_in[0];
  const float* K = (const float*)d_in[1];
  const float* V = (const float*)d_in[2];
  float* O = (float*)d_out;
  (void)in_sizes; (void)n_in; (void)out_size;

  const bool split = ws_size >= PART_FLOATS * sizeof(float);
  if (split) {
    fa_split<<<512, 512, 0, stream>>>(Q, K, V, O, (float*)d_ws, 1);
    fa_merge<<<2048, 256, 0, stream>>>((const float*)d_ws, O);
  } else {
    fa_split<<<256, 512, 0, stream>>>(Q, K, V, O, (float*)d_ws, 0);
  }
}

// Round 19
// 49.936 us; speedup vs baseline: 1.0524x; 1.0524x over previous
//
#include <hip/hip_runtime.h>
#include <hip/hip_bf16.h>

namespace {

constexpr int B_ = 4, L = 2048, H = 8, E = 64;
constexpr int RS = H * E;            // 512 floats: row stride in [B,L,H,E]
constexpr float CS = 0.125f * 1.44269504f;  // SCALE * log2(e): exp2-direct
constexpr float THR2 = 11.5f;        // defer-max threshold in log2 units

// split-K partials (floats): acc[2][32][1024rows][64] ++ m ++ l  (R11 layout)
constexpr size_t ACCF = (size_t)2 * 32 * 8 * 128 * 64;
constexpr size_t MOFF = ACCF;
constexpr size_t PART_ROWS = (size_t)32 * 8 * 128;
constexpr size_t LOFF = MOFF + 2 * PART_ROWS;
constexpr size_t PART_FLOATS = LOFF + 2 * PART_ROWS;   // ~17.3 MB

typedef __attribute__((ext_vector_type(8))) short bf16x8;
typedef __attribute__((ext_vector_type(4))) float f32x4;

__device__ inline unsigned cvt2(float a, float b) {
  __hip_bfloat162 hh = __float22bfloat162_rn(make_float2(a, b));  // v_cvt_pk_bf16_f32
  union { __hip_bfloat162 h; unsigned u; } c; c.h = hh; return c.u;
}

// Best verified configuration (R17, 49.9 us): 512 blocks x 8 waves, pair
// (g,15-g), two uniform 17-step roles, QBLK=16, KVBLK=64, swapped
// S^T = K*Q^T, exp2-domain softmax, defer-max, ones-column lsum MFMA,
// conflict-free LDS swizzles, s_setprio around compute, incremental
// staging cursors, one barrier per step (2 independent domains/CU).
__global__ __launch_bounds__(512)
void fa_split(const float* __restrict__ Q, const float* __restrict__ K,
              const float* __restrict__ V, float* __restrict__ O,
              float* __restrict__ ws, int splitMode)
{
  const int tid  = (int)threadIdx.x;
  const int lane = tid & 63;
  const int wv   = tid >> 6;
  const int bi   = (int)blockIdx.x;
  const int bh   = bi & 31;                 // low bits -> XCD L2 locality
  const int pp   = (bi >> 5) & 7;
  const int role = splitMode ? (bi >> 8) : 2;
  const int b = bh >> 3, h = bh & 7;
  const int ln = lane & 15, lg = lane >> 4, d0 = lg * 4;

  // schedule (64-key steps)
  int total, ph1sb0, qgA, k0A, qgB; bool finA, finB; int part;
  const int g = pp, v = 15 - pp;
  if (role == 0)      { total = 17; ph1sb0 = 2*g+2; qgA = g; k0A = 0;        finA = true;  qgB = v; finB = false; part = 0; }
  else if (role == 1) { total = 17; ph1sb0 = 1000;  qgA = v; k0A = 15 - 2*g; finA = false; qgB = 0; finB = false; part = 1; }
  else                { total = 34; ph1sb0 = 2*g+2; qgA = g; k0A = 0;        finA = true;  qgB = v; finB = true;  part = 0; }

  const size_t base = (size_t)b * L * RS + (size_t)h * E;
  const float* Qb = Q + base;
  const float* Kb = K + base;
  const float* Vb = V + base;
  float*       Ob = O + base;

  __shared__ __align__(16) unsigned char KT[2][64 * 128];
  __shared__ __align__(16) unsigned char VT[2][64 * 128];

  // ---- staging: incremental pointers, one uint4 LDS write each ----
  const int vdd = tid & 63, vc = tid >> 6;          // V: dim vdd, chunk vc
  const int vkb = 4 * vc + ((vc >> 2) << 4);        // keys vkb..+3, vkb+16..+19
  const int kky = tid >> 3, kc = tid & 7;           // K: key kky, dims 8kc..+7
  float vr[8]; float4 kr0, kr1;
  const float* vp_it;                                // incremental cursors
  const float* kp_it;

  auto stage_seek = [&](int ks) {                    // rebuild cursors (rare)
    const int kv0 = ks * 64;
    vp_it = Vb + (size_t)(kv0 + vkb) * RS + vdd;
    kp_it = Kb + (size_t)(kv0 + kky) * RS + 8 * kc;
  };
  auto stage_load = [&]() {                          // load at cursor, advance
#pragma unroll
    for (int j = 0; j < 4; ++j) vr[j] = vp_it[(size_t)j * RS];
#pragma unroll
    for (int j = 0; j < 4; ++j) vr[4 + j] = vp_it[(size_t)(16 + j) * RS];
    kr0 = *(const float4*)kp_it; kr1 = *(const float4*)(kp_it + 4);
    vp_it += (size_t)64 * RS;
    kp_it += (size_t)64 * RS;
  };
  auto stage_write = [&](int bufI) {
    union { uint4 q; unsigned u[4]; } w;
    w.u[0] = cvt2(vr[0], vr[1]); w.u[1] = cvt2(vr[2], vr[3]);
    w.u[2] = cvt2(vr[4], vr[5]); w.u[3] = cvt2(vr[6], vr[7]);
    *(uint4*)(VT[bufI] + vdd * 128 + 16 * (vc ^ (vdd & 7))) = w.q;
    union { uint4 q; unsigned u[4]; } y;
    y.u[0] = cvt2(kr0.x, kr0.y); y.u[1] = cvt2(kr0.z, kr0.w);
    y.u[2] = cvt2(kr1.x, kr1.y); y.u[3] = cvt2(kr1.z, kr1.w);
    *(uint4*)(KT[bufI] + kky * 128 + 16 * (kc ^ (kky & 7))) = y.q;
  };

  // ---- per-phase state ----
  int qg = qgA; bool curFin = finA;
  int qrow0 = qg * 128 + wv * 16;
  int nsW   = (qrow0 + 79) >> 6;

  bf16x8 qf0, qf1;
  auto load_q = [&]() {                      // Q pre-scaled by CS (exp2 domain)
    const float* qp = Qb + (size_t)(qrow0 + ln) * RS + 8 * lg;
    float4 a = *(const float4*)qp,        c = *(const float4*)(qp + 4);
    float4 d = *(const float4*)(qp + 32), e = *(const float4*)(qp + 36);
    union { bf16x8 v8; unsigned u[4]; } r0, r1;
    r0.u[0] = cvt2(a.x * CS, a.y * CS); r0.u[1] = cvt2(a.z * CS, a.w * CS);
    r0.u[2] = cvt2(c.x * CS, c.y * CS); r0.u[3] = cvt2(c.z * CS, c.w * CS);
    r1.u[0] = cvt2(d.x * CS, d.y * CS); r1.u[1] = cvt2(d.z * CS, d.w * CS);
    r1.u[2] = cvt2(e.x * CS, e.y * CS); r1.u[3] = cvt2(e.z * CS, e.w * CS);
    qf0 = r0.v8; qf1 = r1.v8;
  };
  load_q();

  // ones fragment for the lsum column (bf16 1.0 = 0x3F80)
  union { bf16x8 v8; unsigned u[4]; } ones;
#pragma unroll
  for (int j = 0; j < 4; ++j) ones.u[j] = 0x3F803F80u;

  f32x4 acc[4], acc4;
#pragma unroll
  for (int nt = 0; nt < 4; ++nt) acc[nt] = (f32x4){0.f, 0.f, 0.f, 0.f};
  acc4 = (f32x4){0.f, 0.f, 0.f, 0.f};       // acc4[r] = lsum of q-row d0+r
  float m = -1e30f;

  auto epilogue = [&]() {
    if (curFin) {
#pragma unroll
      for (int r = 0; r < 4; ++r) {
        const float il = 1.0f / acc4[r];
#pragma unroll
        for (int nt = 0; nt < 4; ++nt)
          Ob[(size_t)(qrow0 + d0 + r) * RS + (ln + 16 * nt)] = acc[nt][r] * il;
      }
    } else {
      const int vg = qg - 8;
      const size_t rb = ((size_t)part * 32 + bh) * 1024 + (size_t)vg * 128;
#pragma unroll
      for (int nt = 0; nt < 4; ++nt)
#pragma unroll
        for (int r = 0; r < 4; ++r)
          ws[(rb + wv * 16 + d0 + r) * 64 + ln + 16 * nt] = acc[nt][r];
      if (lane < 16) ws[MOFF + rb + wv * 16 + lane] = m;
      if (ln == 0) {
#pragma unroll
        for (int r = 0; r < 4; ++r)
          ws[LOFF + rb + wv * 16 + d0 + r] = acc4[r];
      }
    }
  };

  stage_seek(k0A);
  stage_load();
  stage_write(0);
  __syncthreads();
  int buf = 0;

  for (int sb = 0; sb < total; ++sb) {
    const bool haveNext = (sb + 1) < total;
    if (haveNext) {
      if (sb + 1 == ph1sb0) stage_seek(0);   // phase-B restart (rare)
      stage_load();                          // T14: issue early
    }
    const int kstep = (sb < ph1sb0) ? (k0A + sb) : (sb - ph1sb0);

    if (kstep < nsW) {
      __builtin_amdgcn_s_setprio(1);         // T5: favor compute waves
      const unsigned char* Kt = KT[buf];
      const int swzr = 16 * (ln & 7);

      f32x4 st[4];
#pragma unroll
      for (int kt = 0; kt < 4; ++kt) {
        const unsigned char* kr = Kt + (16 * kt + ln) * 128;
        const bf16x8 kfa = *(const bf16x8*)(kr + ((16 * lg) ^ swzr));
        const bf16x8 kfb = *(const bf16x8*)(kr + ((16 * lg + 64) ^ swzr));
        f32x4 s = (f32x4){0.f, 0.f, 0.f, 0.f};
        s = __builtin_amdgcn_mfma_f32_16x16x32_bf16(kfa, qf0, s, 0, 0, 0);
        s = __builtin_amdgcn_mfma_f32_16x16x32_bf16(kfb, qf1, s, 0, 0, 0);
        st[kt] = s;
      }

      float x[16];
#pragma unroll
      for (int kt = 0; kt < 4; ++kt)
#pragma unroll
        for (int r = 0; r < 4; ++r) x[4 * kt + r] = st[kt][r];

      if (kstep == nsW - 1) {                // diagonal tile
        const int kv0 = kstep * 64;
        const int qr = qrow0 + ln;
#pragma unroll
        for (int kt = 0; kt < 4; ++kt)
#pragma unroll
          for (int r = 0; r < 4; ++r) {
            const int key = kv0 + 16 * kt + d0 + r;
            if (key > qr) x[4 * kt + r] = -1e30f;
          }
      }

      // per-lane max (tree); rescale only on rare threshold breach
      float t8[8];
#pragma unroll
      for (int e = 0; e < 8; ++e) t8[e] = fmaxf(x[e], x[8 + e]);
      float t4a = fmaxf(t8[0], t8[4]), t4b = fmaxf(t8[1], t8[5]);
      float t4c = fmaxf(t8[2], t8[6]), t4d = fmaxf(t8[3], t8[7]);
      float mx = fmaxf(fmaxf(t4a, t4b), fmaxf(t4c, t4d));

      if (!__all(mx <= m + THR2)) {
        float gm = fmaxf(mx, __shfl_xor(mx, 16, 64));
        gm = fmaxf(gm, __shfl_xor(gm, 32, 64));
        const float newm = fmaxf(m, gm);
        const float sc = __builtin_exp2f(m - newm);
        float scr[4];
#pragma unroll
        for (int r = 0; r < 4; ++r) scr[r] = __shfl(sc, d0 + r, 64);
#pragma unroll
        for (int nt = 0; nt < 4; ++nt) {
          acc[nt][0] *= scr[0]; acc[nt][1] *= scr[1];
          acc[nt][2] *= scr[2]; acc[nt][3] *= scr[3];
        }
        acc4[0] *= scr[0]; acc4[1] *= scr[1];
        acc4[2] *= scr[2]; acc4[3] *= scr[3];
        m = newm;
      }

      float p[16];
#pragma unroll
      for (int e = 0; e < 16; ++e) p[e] = __builtin_exp2f(x[e] - m);

      // PV (+ ones column for lsum): 2 key-groups x (4 dim-tiles + 1)
      const unsigned char* Vt = VT[buf];
#pragma unroll
      for (int kg = 0; kg < 2; ++kg) {
        union { bf16x8 v8; unsigned u[4]; } pf;
#pragma unroll
        for (int j = 0; j < 4; ++j)
          pf.u[j] = cvt2(p[8 * kg + 2 * j], p[8 * kg + 2 * j + 1]);
#pragma unroll
        for (int nt = 0; nt < 4; ++nt) {
          const int row = ln + 16 * nt;
          const bf16x8 vf = *(const bf16x8*)(
              Vt + row * 128 + 16 * ((lg + 4 * kg) ^ (ln & 7)));
          acc[nt] = __builtin_amdgcn_mfma_f32_16x16x32_bf16(pf.v8, vf, acc[nt], 0, 0, 0);
        }
        acc4 = __builtin_amdgcn_mfma_f32_16x16x32_bf16(pf.v8, ones.v8, acc4, 0, 0, 0);
      }
      __builtin_amdgcn_s_setprio(0);
    }

    if (sb == ph1sb0 - 1) {                  // phase boundary (block-uniform)
      epilogue();
#pragma unroll
      for (int nt = 0; nt < 4; ++nt) acc[nt] = (f32x4){0.f, 0.f, 0.f, 0.f};
      acc4 = (f32x4){0.f, 0.f, 0.f, 0.f};
      m = -1e30f;
      qg = qgB; curFin = finB;
      qrow0 = qg * 128 + wv * 16;
      nsW = (qrow0 + 79) >> 6;
      load_q();
    }

    if (haveNext) stage_write(buf ^ 1);
    __syncthreads();
    buf ^= 1;
  }

  epilogue();
}

// Combine the two split-K partials for rows 1024..2047 (VERBATIM from R11).
__global__ __launch_bounds__(256)
void fa_merge(const float* __restrict__ ws, float* __restrict__ O)
{
  const int idx = (int)blockIdx.x * 256 + (int)threadIdx.x;   // 0..524287
  const int d4  = idx & 15;
  const int row = (idx >> 4) & 127;
  const int vg  = (idx >> 11) & 7;
  const int bh  = idx >> 14;
  const size_t rbase = ((size_t)bh * 8 + vg) * 128 + row;

  const float m0 = ws[MOFF + rbase],             l0 = ws[LOFF + rbase];
  const float m1 = ws[MOFF + PART_ROWS + rbase], l1 = ws[LOFF + PART_ROWS + rbase];
  const float M  = fmaxf(m0, m1);
  const float e0 = __builtin_exp2f(m0 - M), e1 = __builtin_exp2f(m1 - M);
  const float inv = 1.0f / (l0 * e0 + l1 * e1);

  const float4 a0 = *(const float4*)(ws + rbase * 64 + 4 * d4);
  const float4 a1 = *(const float4*)(ws + PART_ROWS * 64 + rbase * 64 + 4 * d4);

  const int b = bh >> 3, h = bh & 7;
  const int orow = (8 + vg) * 128 + row;
  float4 o;
  o.x = (a0.x * e0 + a1.x * e1) * inv;
  o.y = (a0.y * e0 + a1.y * e1) * inv;
  o.z = (a0.z * e0 + a1.z * e1) * inv;
  o.w = (a0.w * e0 + a1.w * e1) * inv;
  *(float4*)(O + ((size_t)(b * L + orow) * H + h) * E + 4 * d4) = o;
}

} // namespace

extern "C" void kernel_launch(void* const* d_in, const int* in_sizes, int n_in,
                              void* d_out, int out_size, void* d_ws, size_t ws_size,
                              hipStream_t stream) {
  const float* Q = (const float*)d_in[0];
  const float* K = (const float*)d_in[1];
  const float* V = (const float*)d_in[2];
  float* O = (float*)d_out;
  (void)in_sizes; (void)n_in; (void)out_size;

  const bool split = ws_size >= PART_FLOATS * sizeof(float);
  if (split) {
    fa_split<<<512, 512, 0, stream>>>(Q, K, V, O, (float*)d_ws, 1);
    fa_merge<<<2048, 256, 0, stream>>>((const float*)d_ws, O);
  } else {
    fa_split<<<256, 512, 0, stream>>>(Q, K, V, O, (float*)d_ws, 0);
  }
}